// Round 1
// baseline (925.170 us; speedup 1.0000x reference)
//
#include <hip/hip_runtime.h>

#define NC 100000
#define NU 100000
#define NE 1600000
#define DC 256
#define DU 128
#define HID 128
#define OUTD 64

// ---------------------------------------------------------------------------
// K0: Wlo = Wl@Wo, Wro = Wr@Wo, b2 = bl@Wo + bo   (tiny, 128 blocks x 64 thr)
// ---------------------------------------------------------------------------
__global__ void prep_kernel(const float* __restrict__ Wl, const float* __restrict__ bl,
                            const float* __restrict__ Wr, const float* __restrict__ Wo,
                            const float* __restrict__ bo,
                            float* __restrict__ Wlo, float* __restrict__ Wro,
                            float* __restrict__ b2) {
    const int k = blockIdx.x;   // 0..127
    const int f = threadIdx.x;  // 0..63
    float a0 = 0.f, a1 = 0.f;
    for (int m = 0; m < HID; ++m) {
        float wo = Wo[m * OUTD + f];
        a0 = fmaf(Wl[k * HID + m], wo, a0);
        a1 = fmaf(Wr[k * HID + m], wo, a1);
    }
    Wlo[k * OUTD + f] = a0;
    Wro[k * OUTD + f] = a1;
    if (k == 0) {
        float s = bo[f];
        for (int m = 0; m < HID; ++m) s = fmaf(bl[m], Wo[m * OUTD + f], s);
        b2[f] = s;
    }
}

// ---------------------------------------------------------------------------
// K1: p_u = relu(x_u @ Wu + bu) @ Wlo    [NU x 64]
// block = 128 threads, 8 nodes per tile, register-blocked (8 acc per thread)
// ---------------------------------------------------------------------------
__global__ void __launch_bounds__(128) user_proj(const float* __restrict__ xu,
                                                 const float* __restrict__ Wu,
                                                 const float* __restrict__ bu,
                                                 const float* __restrict__ Wlo,
                                                 float* __restrict__ pu) {
    __shared__ float xs[8][DU];
    __shared__ float hs[8][HID];
    const int j = threadIdx.x;  // feature 0..127
    const float bj = bu[j];
    for (int base = blockIdx.x * 8; base < NU; base += gridDim.x * 8) {
        // stage 8 rows of x (8*128 floats = 256 float4, 2 per thread)
#pragma unroll
        for (int r = 0; r < 2; ++r) {
            int idx = r * 128 + j;          // 0..255
            int node = idx >> 5, c4 = idx & 31;
            ((float4*)&xs[node][0])[c4] =
                ((const float4*)(xu + (size_t)(base + node) * DU))[c4];
        }
        __syncthreads();
        float acc[8] = {bj, bj, bj, bj, bj, bj, bj, bj};
        for (int k = 0; k < DU; ++k) {
            float w = Wu[k * HID + j];
#pragma unroll
            for (int n = 0; n < 8; ++n) acc[n] = fmaf(xs[n][k], w, acc[n]);
        }
#pragma unroll
        for (int n = 0; n < 8; ++n) hs[n][j] = fmaxf(acc[n], 0.f);
        __syncthreads();
        // second GEMM: thread = (n2, f); n2 picks 4 nodes, f is out feature
        const int f = j & 63, n2 = j >> 6;
        float a2[4] = {0.f, 0.f, 0.f, 0.f};
        for (int k = 0; k < HID; ++k) {
            float w = Wlo[k * OUTD + f];
#pragma unroll
            for (int n = 0; n < 4; ++n) a2[n] = fmaf(hs[n2 * 4 + n][k], w, a2[n]);
        }
#pragma unroll
        for (int n = 0; n < 4; ++n)
            pu[(size_t)(base + n2 * 4 + n) * OUTD + f] = a2[n];
        __syncthreads();
    }
}

// ---------------------------------------------------------------------------
// K2: out = relu(x_c @ Wc + bc) @ Wro + b2    [NC x 64]  (mean added later)
// ---------------------------------------------------------------------------
__global__ void __launch_bounds__(128) content_proj(const float* __restrict__ xc,
                                                    const float* __restrict__ Wc,
                                                    const float* __restrict__ bc,
                                                    const float* __restrict__ Wro,
                                                    const float* __restrict__ b2,
                                                    float* __restrict__ out) {
    __shared__ float xs[8][DC];
    __shared__ float hs[8][HID];
    const int j = threadIdx.x;
    const float bj = bc[j];
    for (int base = blockIdx.x * 8; base < NC; base += gridDim.x * 8) {
        // stage 8 rows of x (8*256 floats = 512 float4, 4 per thread)
#pragma unroll
        for (int r = 0; r < 4; ++r) {
            int idx = r * 128 + j;          // 0..511
            int node = idx >> 6, c4 = idx & 63;
            ((float4*)&xs[node][0])[c4] =
                ((const float4*)(xc + (size_t)(base + node) * DC))[c4];
        }
        __syncthreads();
        float acc[8] = {bj, bj, bj, bj, bj, bj, bj, bj};
        for (int k = 0; k < DC; ++k) {
            float w = Wc[k * HID + j];
#pragma unroll
            for (int n = 0; n < 8; ++n) acc[n] = fmaf(xs[n][k], w, acc[n]);
        }
#pragma unroll
        for (int n = 0; n < 8; ++n) hs[n][j] = fmaxf(acc[n], 0.f);
        __syncthreads();
        const int f = j & 63, n2 = j >> 6;
        const float bf = b2[f];
        float a2[4] = {bf, bf, bf, bf};
        for (int k = 0; k < HID; ++k) {
            float w = Wro[k * OUTD + f];
#pragma unroll
            for (int n = 0; n < 4; ++n) a2[n] = fmaf(hs[n2 * 4 + n][k], w, a2[n]);
        }
#pragma unroll
        for (int n = 0; n < 4; ++n)
            out[(size_t)(base + n2 * 4 + n) * OUTD + f] = a2[n];
        __syncthreads();
    }
}

// ---------------------------------------------------------------------------
// K3: degree count
// ---------------------------------------------------------------------------
__global__ void degree_kernel(const int* __restrict__ dst, int* __restrict__ cnt) {
    int i = blockIdx.x * blockDim.x + threadIdx.x;
    int stride = gridDim.x * blockDim.x;
    for (; i < NE; i += stride) atomicAdd(&cnt[dst[i]], 1);
}

// ---------------------------------------------------------------------------
// K4: scatter p_u[src] into agg[dst] (one wave per edge, lane = feature)
// ---------------------------------------------------------------------------
__global__ void scatter_kernel(const int* __restrict__ src, const int* __restrict__ dst,
                               const float* __restrict__ pu, float* __restrict__ agg) {
    int wave = (int)((blockIdx.x * blockDim.x + threadIdx.x) >> 6);
    int lane = threadIdx.x & 63;
    int nwaves = (int)((gridDim.x * blockDim.x) >> 6);
    for (int e = wave; e < NE; e += nwaves) {
        int s = src[e], d = dst[e];
        atomicAdd(&agg[(size_t)d * OUTD + lane], pu[(size_t)s * OUTD + lane]);
    }
}

// ---------------------------------------------------------------------------
// K5: out += agg / max(cnt,1)
// ---------------------------------------------------------------------------
__global__ void finalize_kernel(const float* __restrict__ agg, const int* __restrict__ cnt,
                                float* __restrict__ out) {
    int i = blockIdx.x * blockDim.x + threadIdx.x;
    int stride = gridDim.x * blockDim.x;
    for (; i < NC * OUTD; i += stride) {
        float c = (float)max(cnt[i >> 6], 1);
        out[i] += agg[i] / c;
    }
}

extern "C" void kernel_launch(void* const* d_in, const int* in_sizes, int n_in,
                              void* d_out, int out_size, void* d_ws, size_t ws_size,
                              hipStream_t stream) {
    const float* xc = (const float*)d_in[0];
    const float* xu = (const float*)d_in[1];
    const int*   ei = (const int*)d_in[2];
    const float* Wc = (const float*)d_in[3];
    const float* bc = (const float*)d_in[4];
    const float* Wu = (const float*)d_in[5];
    const float* bu = (const float*)d_in[6];
    const float* Wl = (const float*)d_in[7];
    const float* bl = (const float*)d_in[8];
    const float* Wr = (const float*)d_in[9];
    const float* Wo = (const float*)d_in[10];
    const float* bo = (const float*)d_in[11];
    float* out = (float*)d_out;

    const int* esrc = ei;        // edge_index[0] = user ids
    const int* edst = ei + NE;   // edge_index[1] = content ids

    // workspace carve (all 16B aligned)
    float* pu  = (float*)d_ws;                        // NU*64 floats
    float* agg = pu + (size_t)NU * OUTD;              // NC*64 floats
    int*   cnt = (int*)(agg + (size_t)NC * OUTD);     // NC ints
    float* Wlo = (float*)(cnt + NC);                  // 128*64
    float* Wro = Wlo + HID * OUTD;                    // 128*64
    float* b2  = Wro + HID * OUTD;                    // 64

    // zero agg + cnt in one contiguous memset
    hipMemsetAsync(agg, 0, (size_t)NC * OUTD * sizeof(float) + (size_t)NC * sizeof(int),
                   stream);

    prep_kernel<<<HID, OUTD, 0, stream>>>(Wl, bl, Wr, Wo, bo, Wlo, Wro, b2);
    user_proj<<<2048, 128, 0, stream>>>(xu, Wu, bu, Wlo, pu);
    content_proj<<<2048, 128, 0, stream>>>(xc, Wc, bc, Wro, b2, out);
    degree_kernel<<<1024, 256, 0, stream>>>(edst, cnt);
    scatter_kernel<<<2048, 256, 0, stream>>>(esrc, edst, pu, agg);
    finalize_kernel<<<4096, 256, 0, stream>>>(agg, cnt, out);
}

// Round 2
// 766.896 us; speedup vs baseline: 1.2064x; 1.2064x over previous
//
#include <hip/hip_runtime.h>

#define NC 100000
#define NU 100000
#define NE 1600000
#define DC 256
#define DU 128
#define HID 128
#define OUTD 64
#define SCAN_TILE 1024
#define NBLK ((NC + SCAN_TILE - 1) / SCAN_TILE)   // 98

// ---------------------------------------------------------------------------
// K0: Wlo = Wl@Wo, Wro = Wr@Wo, b2 = bl@Wo + bo
// ---------------------------------------------------------------------------
__global__ void prep_kernel(const float* __restrict__ Wl, const float* __restrict__ bl,
                            const float* __restrict__ Wr, const float* __restrict__ Wo,
                            const float* __restrict__ bo,
                            float* __restrict__ Wlo, float* __restrict__ Wro,
                            float* __restrict__ b2) {
    const int k = blockIdx.x;   // 0..127
    const int f = threadIdx.x;  // 0..63
    float a0 = 0.f, a1 = 0.f;
    for (int m = 0; m < HID; ++m) {
        float wo = Wo[m * OUTD + f];
        a0 = fmaf(Wl[k * HID + m], wo, a0);
        a1 = fmaf(Wr[k * HID + m], wo, a1);
    }
    Wlo[k * OUTD + f] = a0;
    Wro[k * OUTD + f] = a1;
    if (k == 0) {
        float s = bo[f];
        for (int m = 0; m < HID; ++m) s = fmaf(bl[m], Wo[m * OUTD + f], s);
        b2[f] = s;
    }
}

// ---------------------------------------------------------------------------
// K1: p_u = relu(x_u @ Wu + bu) @ Wlo    [NU x 64]
// ---------------------------------------------------------------------------
__global__ void __launch_bounds__(128) user_proj(const float* __restrict__ xu,
                                                 const float* __restrict__ Wu,
                                                 const float* __restrict__ bu,
                                                 const float* __restrict__ Wlo,
                                                 float* __restrict__ pu) {
    __shared__ float xs[8][DU];
    __shared__ float hs[8][HID];
    const int j = threadIdx.x;  // feature 0..127
    const float bj = bu[j];
    for (int base = blockIdx.x * 8; base < NU; base += gridDim.x * 8) {
#pragma unroll
        for (int r = 0; r < 2; ++r) {
            int idx = r * 128 + j;
            int node = idx >> 5, c4 = idx & 31;
            ((float4*)&xs[node][0])[c4] =
                ((const float4*)(xu + (size_t)(base + node) * DU))[c4];
        }
        __syncthreads();
        float acc[8] = {bj, bj, bj, bj, bj, bj, bj, bj};
        for (int k = 0; k < DU; ++k) {
            float w = Wu[k * HID + j];
#pragma unroll
            for (int n = 0; n < 8; ++n) acc[n] = fmaf(xs[n][k], w, acc[n]);
        }
#pragma unroll
        for (int n = 0; n < 8; ++n) hs[n][j] = fmaxf(acc[n], 0.f);
        __syncthreads();
        const int f = j & 63, n2 = j >> 6;
        float a2[4] = {0.f, 0.f, 0.f, 0.f};
        for (int k = 0; k < HID; ++k) {
            float w = Wlo[k * OUTD + f];
#pragma unroll
            for (int n = 0; n < 4; ++n) a2[n] = fmaf(hs[n2 * 4 + n][k], w, a2[n]);
        }
#pragma unroll
        for (int n = 0; n < 4; ++n)
            pu[(size_t)(base + n2 * 4 + n) * OUTD + f] = a2[n];
        __syncthreads();
    }
}

// ---------------------------------------------------------------------------
// K2: out = relu(x_c @ Wc + bc) @ Wro + b2    [NC x 64]  (mean added by K8)
// ---------------------------------------------------------------------------
__global__ void __launch_bounds__(128) content_proj(const float* __restrict__ xc,
                                                    const float* __restrict__ Wc,
                                                    const float* __restrict__ bc,
                                                    const float* __restrict__ Wro,
                                                    const float* __restrict__ b2,
                                                    float* __restrict__ out) {
    __shared__ float xs[8][DC];
    __shared__ float hs[8][HID];
    const int j = threadIdx.x;
    const float bj = bc[j];
    for (int base = blockIdx.x * 8; base < NC; base += gridDim.x * 8) {
#pragma unroll
        for (int r = 0; r < 4; ++r) {
            int idx = r * 128 + j;
            int node = idx >> 6, c4 = idx & 63;
            ((float4*)&xs[node][0])[c4] =
                ((const float4*)(xc + (size_t)(base + node) * DC))[c4];
        }
        __syncthreads();
        float acc[8] = {bj, bj, bj, bj, bj, bj, bj, bj};
        for (int k = 0; k < DC; ++k) {
            float w = Wc[k * HID + j];
#pragma unroll
            for (int n = 0; n < 8; ++n) acc[n] = fmaf(xs[n][k], w, acc[n]);
        }
#pragma unroll
        for (int n = 0; n < 8; ++n) hs[n][j] = fmaxf(acc[n], 0.f);
        __syncthreads();
        const int f = j & 63, n2 = j >> 6;
        const float bf = b2[f];
        float a2[4] = {bf, bf, bf, bf};
        for (int k = 0; k < HID; ++k) {
            float w = Wro[k * OUTD + f];
#pragma unroll
            for (int n = 0; n < 4; ++n) a2[n] = fmaf(hs[n2 * 4 + n][k], w, a2[n]);
        }
#pragma unroll
        for (int n = 0; n < 4; ++n)
            out[(size_t)(base + n2 * 4 + n) * OUTD + f] = a2[n];
        __syncthreads();
    }
}

// ---------------------------------------------------------------------------
// K3: degree histogram (int atomics, int4 edge reads)
// ---------------------------------------------------------------------------
__global__ void degree_kernel(const int* __restrict__ dst, int* __restrict__ cnt) {
    int i = blockIdx.x * blockDim.x + threadIdx.x;
    int stride = gridDim.x * blockDim.x;
    for (; i < NE / 4; i += stride) {
        int4 d = ((const int4*)dst)[i];
        atomicAdd(&cnt[d.x], 1);
        atomicAdd(&cnt[d.y], 1);
        atomicAdd(&cnt[d.z], 1);
        atomicAdd(&cnt[d.w], 1);
    }
}

// ---------------------------------------------------------------------------
// K4-K6: exclusive scan of cnt[NC] -> off[NC+1] (and cursor copy)
// ---------------------------------------------------------------------------
__global__ void scan1(const int* __restrict__ cnt, int* __restrict__ bsum) {
    __shared__ int red[4];
    int t = threadIdx.x;
    int base = blockIdx.x * SCAN_TILE + t * 4;
    int s = 0;
#pragma unroll
    for (int k = 0; k < 4; ++k) { int i = base + k; if (i < NC) s += cnt[i]; }
#pragma unroll
    for (int m = 1; m < 64; m <<= 1) s += __shfl_xor(s, m, 64);
    if ((t & 63) == 0) red[t >> 6] = s;
    __syncthreads();
    if (t == 0) bsum[blockIdx.x] = red[0] + red[1] + red[2] + red[3];
}

__global__ void scan2(const int* __restrict__ bsum, int* __restrict__ boff,
                      int* __restrict__ off) {
    if (threadIdx.x == 0) {
        int run = 0;
        for (int i = 0; i < NBLK; ++i) { boff[i] = run; run += bsum[i]; }
        off[NC] = run;  // == NE
    }
}

__global__ void scan3(const int* __restrict__ cnt, const int* __restrict__ boff,
                      int* __restrict__ off, int* __restrict__ cursor) {
    __shared__ int ts[256];
    int t = threadIdx.x;
    int base = blockIdx.x * SCAN_TILE + t * 4;
    int v[4]; int s = 0;
#pragma unroll
    for (int k = 0; k < 4; ++k) {
        int i = base + k;
        v[k] = (i < NC) ? cnt[i] : 0;
        s += v[k];
    }
    ts[t] = s;
    __syncthreads();
    for (int d = 1; d < 256; d <<= 1) {
        int x = (t >= d) ? ts[t - d] : 0;
        __syncthreads();
        ts[t] += x;
        __syncthreads();
    }
    int run = boff[blockIdx.x] + ts[t] - s;  // exclusive prefix for this thread
#pragma unroll
    for (int k = 0; k < 4; ++k) {
        int i = base + k;
        if (i < NC) { off[i] = run; cursor[i] = run; run += v[k]; }
    }
}

// ---------------------------------------------------------------------------
// K7: place edges into CSR order (src ids sorted by dst)
// ---------------------------------------------------------------------------
__global__ void place_kernel(const int* __restrict__ src, const int* __restrict__ dst,
                             int* __restrict__ cursor, int* __restrict__ ssrc) {
    int i = blockIdx.x * blockDim.x + threadIdx.x;
    int stride = gridDim.x * blockDim.x;
    for (; i < NE; i += stride) {
        int p = atomicAdd(&cursor[dst[i]], 1);
        ssrc[p] = src[i];
    }
}

// ---------------------------------------------------------------------------
// K8: gather-aggregate + mean + add into out. One wave per content node.
// Lane layout: g = lane>>4 (edge slot 0..3), f4 = lane&15 (float4 chunk).
// ---------------------------------------------------------------------------
__global__ void __launch_bounds__(256) gather_agg(const int* __restrict__ ssrc,
                                                  const int* __restrict__ off,
                                                  const float* __restrict__ pu,
                                                  float* __restrict__ out) {
    int node = blockIdx.x * 4 + (threadIdx.x >> 6);
    if (node >= NC) return;
    int lane = threadIdx.x & 63;
    int g = lane >> 4;
    int f4 = lane & 15;
    int e0 = off[node], e1 = off[node + 1];
    float4 acc = {0.f, 0.f, 0.f, 0.f};
    for (int e = e0 + g; e < e1; e += 4) {
        int s = ssrc[e];
        float4 v = ((const float4*)pu)[(size_t)s * 16 + f4];
        acc.x += v.x; acc.y += v.y; acc.z += v.z; acc.w += v.w;
    }
    // reduce across the 4 edge slots (lanes differing in bits 4,5)
#pragma unroll
    for (int m = 16; m <= 32; m <<= 1) {
        acc.x += __shfl_xor(acc.x, m, 64);
        acc.y += __shfl_xor(acc.y, m, 64);
        acc.z += __shfl_xor(acc.z, m, 64);
        acc.w += __shfl_xor(acc.w, m, 64);
    }
    if (g == 0) {
        float inv = 1.0f / (float)max(e1 - e0, 1);
        float4* po = (float4*)out + (size_t)node * 16 + f4;
        float4 o = *po;
        o.x += acc.x * inv; o.y += acc.y * inv;
        o.z += acc.z * inv; o.w += acc.w * inv;
        *po = o;
    }
}

extern "C" void kernel_launch(void* const* d_in, const int* in_sizes, int n_in,
                              void* d_out, int out_size, void* d_ws, size_t ws_size,
                              hipStream_t stream) {
    const float* xc = (const float*)d_in[0];
    const float* xu = (const float*)d_in[1];
    const int*   ei = (const int*)d_in[2];
    const float* Wc = (const float*)d_in[3];
    const float* bc = (const float*)d_in[4];
    const float* Wu = (const float*)d_in[5];
    const float* bu = (const float*)d_in[6];
    const float* Wl = (const float*)d_in[7];
    const float* bl = (const float*)d_in[8];
    const float* Wr = (const float*)d_in[9];
    const float* Wo = (const float*)d_in[10];
    const float* bo = (const float*)d_in[11];
    float* out = (float*)d_out;

    const int* esrc = ei;        // edge_index[0] = user ids
    const int* edst = ei + NE;   // edge_index[1] = content ids

    // workspace carve
    float* pu     = (float*)d_ws;                     // NU*64 floats (25.6 MB)
    int*   cnt    = (int*)(pu + (size_t)NU * OUTD);   // NC
    int*   off    = cnt + NC;                         // NC+1
    int*   cursor = off + NC + 1;                     // NC
    int*   bsum   = cursor + NC;                      // NBLK
    int*   boff   = bsum + NBLK;                      // NBLK
    int*   ssrc   = boff + NBLK;                      // NE (6.4 MB)
    float* Wlo    = (float*)(ssrc + NE);              // 128*64
    float* Wro    = Wlo + HID * OUTD;                 // 128*64
    float* b2     = Wro + HID * OUTD;                 // 64

    hipMemsetAsync(cnt, 0, (size_t)NC * sizeof(int), stream);

    prep_kernel<<<HID, OUTD, 0, stream>>>(Wl, bl, Wr, Wo, bo, Wlo, Wro, b2);
    user_proj<<<2048, 128, 0, stream>>>(xu, Wu, bu, Wlo, pu);
    content_proj<<<2048, 128, 0, stream>>>(xc, Wc, bc, Wro, b2, out);
    degree_kernel<<<1024, 256, 0, stream>>>(edst, cnt);
    scan1<<<NBLK, 256, 0, stream>>>(cnt, bsum);
    scan2<<<1, 64, 0, stream>>>(bsum, boff, off);
    scan3<<<NBLK, 256, 0, stream>>>(cnt, boff, off, cursor);
    place_kernel<<<2048, 256, 0, stream>>>(esrc, edst, cursor, ssrc);
    gather_agg<<<(NC + 3) / 4, 256, 0, stream>>>(ssrc, off, pu, out);
}

// Round 3
// 609.594 us; speedup vs baseline: 1.5177x; 1.2580x over previous
//
#include <hip/hip_runtime.h>
#include <hip/hip_bf16.h>

#define NC 100000
#define NU 100000
#define NE 1600000
#define DC 256
#define DU 128
#define HID 128
#define OUTD 64
#define SCAN_TILE 1024
#define NBLK ((NC + SCAN_TILE - 1) / SCAN_TILE)   // 98

typedef __attribute__((ext_vector_type(8))) short bf16x8;
typedef __attribute__((ext_vector_type(4))) float f32x4;

// ---------------------------------------------------------------------------
// K0: Wlo_t = (Wl@Wo)^T bf16, Wro_t = (Wr@Wo)^T bf16, b2 = bl@Wo + bo (fp32)
// ---------------------------------------------------------------------------
__global__ void prep_kernel(const float* __restrict__ Wl, const float* __restrict__ bl,
                            const float* __restrict__ Wr, const float* __restrict__ Wo,
                            const float* __restrict__ bo,
                            __hip_bfloat16* __restrict__ Wlo_t,
                            __hip_bfloat16* __restrict__ Wro_t,
                            float* __restrict__ b2) {
    const int k = blockIdx.x;   // 0..127
    const int f = threadIdx.x;  // 0..63
    float a0 = 0.f, a1 = 0.f;
    for (int m = 0; m < HID; ++m) {
        float wo = Wo[m * OUTD + f];
        a0 = fmaf(Wl[k * HID + m], wo, a0);
        a1 = fmaf(Wr[k * HID + m], wo, a1);
    }
    Wlo_t[f * HID + k] = __float2bfloat16(a0);   // [OUTD][HID]
    Wro_t[f * HID + k] = __float2bfloat16(a1);
    if (k == 0) {
        float s = bo[f];
        for (int m = 0; m < HID; ++m) s = fmaf(bl[m], Wo[m * OUTD + f], s);
        b2[f] = s;
    }
}

// ---------------------------------------------------------------------------
// K0b: transpose + bf16-convert an input-proj weight: Wt[j][k] = W[k][j]
// W is [K x HID] fp32, Wt is [HID x K] bf16
// ---------------------------------------------------------------------------
__global__ void transpose_w(const float* __restrict__ W, __hip_bfloat16* __restrict__ Wt,
                            int K) {
    int i = blockIdx.x * blockDim.x + threadIdx.x;
    int total = K * HID;
    if (i >= total) return;
    int j = i % HID, k = i / HID;
    Wt[j * K + k] = __float2bfloat16(W[k * HID + j]);
}

// ---------------------------------------------------------------------------
// Fused per-node-type MFMA pipeline:
//   p = relu(x @ W1 + b1) @ W2 (+bias2)
// 256 threads = 4 waves; 64-node M-tile (wave w owns rows 16w..16w+15).
// W1t: [HID][DIN] bf16 (k-contiguous)  W2t: [OUTD][HID] bf16
// ---------------------------------------------------------------------------
template <int DIN>
__global__ void __launch_bounds__(256) fused_gemm(const float* __restrict__ x,
                                                  const __hip_bfloat16* __restrict__ W1t,
                                                  const float* __restrict__ b1,
                                                  const __hip_bfloat16* __restrict__ W2t,
                                                  const float* __restrict__ bias2,
                                                  float* __restrict__ outp, int nrows) {
    constexpr int PAD = 8;
    constexpr int XS = DIN + PAD;
    constexpr int HS = HID + PAD;
    __shared__ __align__(16) __hip_bfloat16 x_s[64 * XS];
    __shared__ __align__(16) __hip_bfloat16 h_s[64 * HS];
    const int t = threadIdx.x;
    const int wave = t >> 6, lane = t & 63;
    const int quad = lane >> 4, l16 = lane & 15;
    const int base = blockIdx.x * 64;

    // ---- stage 64 x DIN fp32 -> bf16 LDS tile (coalesced float4 reads) ----
    constexpr int NF4 = 16 * DIN;           // total float4 in tile
    for (int i = t; i < NF4; i += 256) {
        int row = i / (DIN / 4), c4 = i % (DIN / 4);
        float4 v = make_float4(0.f, 0.f, 0.f, 0.f);
        if (base + row < nrows)
            v = ((const float4*)(x + (size_t)(base + row) * DIN))[c4];
        __hip_bfloat16* p = &x_s[row * XS + c4 * 4];
        p[0] = __float2bfloat16(v.x);
        p[1] = __float2bfloat16(v.y);
        p[2] = __float2bfloat16(v.z);
        p[3] = __float2bfloat16(v.w);
    }
    __syncthreads();

    // ---- GEMM1: h = relu(x @ W1 + b1) ----
    f32x4 acc1[HID / 16];
#pragma unroll
    for (int nt = 0; nt < HID / 16; ++nt) acc1[nt] = (f32x4){0.f, 0.f, 0.f, 0.f};
#pragma unroll
    for (int ks = 0; ks < DIN / 32; ++ks) {
        bf16x8 a = *(const bf16x8*)&x_s[(wave * 16 + l16) * XS + ks * 32 + quad * 8];
#pragma unroll
        for (int nt = 0; nt < HID / 16; ++nt) {
            bf16x8 b = *(const bf16x8*)&W1t[(size_t)(nt * 16 + l16) * DIN + ks * 32 + quad * 8];
            acc1[nt] = __builtin_amdgcn_mfma_f32_16x16x32_bf16(a, b, acc1[nt], 0, 0, 0);
        }
    }
    // epilogue 1: +bias, relu, bf16 -> h_s (wave-private rows, no barrier)
#pragma unroll
    for (int nt = 0; nt < HID / 16; ++nt) {
        float bb = b1[nt * 16 + l16];
#pragma unroll
        for (int r = 0; r < 4; ++r) {
            float v = fmaxf(acc1[nt][r] + bb, 0.f);
            h_s[(wave * 16 + quad * 4 + r) * HS + nt * 16 + l16] = __float2bfloat16(v);
        }
    }

    // ---- GEMM2: p = h @ W2 (+bias2) ----
    f32x4 acc2[OUTD / 16];
#pragma unroll
    for (int nt = 0; nt < OUTD / 16; ++nt) acc2[nt] = (f32x4){0.f, 0.f, 0.f, 0.f};
#pragma unroll
    for (int ks = 0; ks < HID / 32; ++ks) {
        bf16x8 a = *(const bf16x8*)&h_s[(wave * 16 + l16) * HS + ks * 32 + quad * 8];
#pragma unroll
        for (int nt = 0; nt < OUTD / 16; ++nt) {
            bf16x8 b = *(const bf16x8*)&W2t[(size_t)(nt * 16 + l16) * HID + ks * 32 + quad * 8];
            acc2[nt] = __builtin_amdgcn_mfma_f32_16x16x32_bf16(a, b, acc2[nt], 0, 0, 0);
        }
    }
    // epilogue 2: +bias2 (optional), fp32 store
#pragma unroll
    for (int nt = 0; nt < OUTD / 16; ++nt) {
        float bb = bias2 ? bias2[nt * 16 + l16] : 0.f;
#pragma unroll
        for (int r = 0; r < 4; ++r) {
            int row = wave * 16 + quad * 4 + r;
            if (base + row < nrows)
                outp[(size_t)(base + row) * OUTD + nt * 16 + l16] = acc2[nt][r] + bb;
        }
    }
}

// ---------------------------------------------------------------------------
// K3: degree histogram (int atomics, int4 edge reads)
// ---------------------------------------------------------------------------
__global__ void degree_kernel(const int* __restrict__ dst, int* __restrict__ cnt) {
    int i = blockIdx.x * blockDim.x + threadIdx.x;
    int stride = gridDim.x * blockDim.x;
    for (; i < NE / 4; i += stride) {
        int4 d = ((const int4*)dst)[i];
        atomicAdd(&cnt[d.x], 1);
        atomicAdd(&cnt[d.y], 1);
        atomicAdd(&cnt[d.z], 1);
        atomicAdd(&cnt[d.w], 1);
    }
}

// ---------------------------------------------------------------------------
// K4-K6: exclusive scan of cnt[NC] -> off[NC+1] (and cursor copy)
// ---------------------------------------------------------------------------
__global__ void scan1(const int* __restrict__ cnt, int* __restrict__ bsum) {
    __shared__ int red[4];
    int t = threadIdx.x;
    int base = blockIdx.x * SCAN_TILE + t * 4;
    int s = 0;
#pragma unroll
    for (int k = 0; k < 4; ++k) { int i = base + k; if (i < NC) s += cnt[i]; }
#pragma unroll
    for (int m = 1; m < 64; m <<= 1) s += __shfl_xor(s, m, 64);
    if ((t & 63) == 0) red[t >> 6] = s;
    __syncthreads();
    if (t == 0) bsum[blockIdx.x] = red[0] + red[1] + red[2] + red[3];
}

__global__ void scan2(const int* __restrict__ bsum, int* __restrict__ boff,
                      int* __restrict__ off) {
    if (threadIdx.x == 0) {
        int run = 0;
        for (int i = 0; i < NBLK; ++i) { boff[i] = run; run += bsum[i]; }
        off[NC] = run;  // == NE
    }
}

__global__ void scan3(const int* __restrict__ cnt, const int* __restrict__ boff,
                      int* __restrict__ off, int* __restrict__ cursor) {
    __shared__ int ts[256];
    int t = threadIdx.x;
    int base = blockIdx.x * SCAN_TILE + t * 4;
    int v[4]; int s = 0;
#pragma unroll
    for (int k = 0; k < 4; ++k) {
        int i = base + k;
        v[k] = (i < NC) ? cnt[i] : 0;
        s += v[k];
    }
    ts[t] = s;
    __syncthreads();
    for (int d = 1; d < 256; d <<= 1) {
        int x = (t >= d) ? ts[t - d] : 0;
        __syncthreads();
        ts[t] += x;
        __syncthreads();
    }
    int run = boff[blockIdx.x] + ts[t] - s;
#pragma unroll
    for (int k = 0; k < 4; ++k) {
        int i = base + k;
        if (i < NC) { off[i] = run; cursor[i] = run; run += v[k]; }
    }
}

// ---------------------------------------------------------------------------
// K7: place edges into CSR order (src ids sorted by dst)
// ---------------------------------------------------------------------------
__global__ void place_kernel(const int* __restrict__ src, const int* __restrict__ dst,
                             int* __restrict__ cursor, int* __restrict__ ssrc) {
    int i = blockIdx.x * blockDim.x + threadIdx.x;
    int stride = gridDim.x * blockDim.x;
    for (; i < NE; i += stride) {
        int p = atomicAdd(&cursor[dst[i]], 1);
        ssrc[p] = src[i];
    }
}

// ---------------------------------------------------------------------------
// K8: gather-aggregate + mean + add into out. One wave per content node.
// ---------------------------------------------------------------------------
__global__ void __launch_bounds__(256) gather_agg(const int* __restrict__ ssrc,
                                                  const int* __restrict__ off,
                                                  const float* __restrict__ pu,
                                                  float* __restrict__ out) {
    int node = blockIdx.x * 4 + (threadIdx.x >> 6);
    if (node >= NC) return;
    int lane = threadIdx.x & 63;
    int g = lane >> 4;
    int f4 = lane & 15;
    int e0 = off[node], e1 = off[node + 1];
    float4 acc = {0.f, 0.f, 0.f, 0.f};
    for (int e = e0 + g; e < e1; e += 4) {
        int s = ssrc[e];
        float4 v = ((const float4*)pu)[(size_t)s * 16 + f4];
        acc.x += v.x; acc.y += v.y; acc.z += v.z; acc.w += v.w;
    }
#pragma unroll
    for (int m = 16; m <= 32; m <<= 1) {
        acc.x += __shfl_xor(acc.x, m, 64);
        acc.y += __shfl_xor(acc.y, m, 64);
        acc.z += __shfl_xor(acc.z, m, 64);
        acc.w += __shfl_xor(acc.w, m, 64);
    }
    if (g == 0) {
        float inv = 1.0f / (float)max(e1 - e0, 1);
        float4* po = (float4*)out + (size_t)node * 16 + f4;
        float4 o = *po;
        o.x += acc.x * inv; o.y += acc.y * inv;
        o.z += acc.z * inv; o.w += acc.w * inv;
        *po = o;
    }
}

extern "C" void kernel_launch(void* const* d_in, const int* in_sizes, int n_in,
                              void* d_out, int out_size, void* d_ws, size_t ws_size,
                              hipStream_t stream) {
    const float* xc = (const float*)d_in[0];
    const float* xu = (const float*)d_in[1];
    const int*   ei = (const int*)d_in[2];
    const float* Wc = (const float*)d_in[3];
    const float* bc = (const float*)d_in[4];
    const float* Wu = (const float*)d_in[5];
    const float* bu = (const float*)d_in[6];
    const float* Wl = (const float*)d_in[7];
    const float* bl = (const float*)d_in[8];
    const float* Wr = (const float*)d_in[9];
    const float* Wo = (const float*)d_in[10];
    const float* bo = (const float*)d_in[11];
    float* out = (float*)d_out;

    const int* esrc = ei;        // edge_index[0] = user ids
    const int* edst = ei + NE;   // edge_index[1] = content ids

    // workspace carve (16B-aligned chunks)
    float* pu     = (float*)d_ws;                       // NU*64 f32 (25.6 MB)
    int*   ssrc   = (int*)(pu + (size_t)NU * OUTD);     // NE
    int*   cnt    = ssrc + NE;                          // NC
    int*   off    = cnt + NC;                           // NC+8 (padded)
    int*   cursor = off + NC + 8;                       // NC
    int*   bsum   = cursor + NC;                        // NBLK
    int*   boff   = bsum + NBLK;                        // NBLK -> pad to 16B
    float* b2     = (float*)(boff + NBLK + 2);          // 64 f32
    __hip_bfloat16* Wlo_t = (__hip_bfloat16*)(b2 + OUTD);     // 64*128
    __hip_bfloat16* Wro_t = Wlo_t + OUTD * HID;               // 64*128
    __hip_bfloat16* Wu_t  = Wro_t + OUTD * HID;               // 128*128
    __hip_bfloat16* Wc_t  = Wu_t + HID * DU;                  // 128*256

    hipMemsetAsync(cnt, 0, (size_t)NC * sizeof(int), stream);

    prep_kernel<<<HID, OUTD, 0, stream>>>(Wl, bl, Wr, Wo, bo, Wlo_t, Wro_t, b2);
    transpose_w<<<(DU * HID + 255) / 256, 256, 0, stream>>>(Wu, Wu_t, DU);
    transpose_w<<<(DC * HID + 255) / 256, 256, 0, stream>>>(Wc, Wc_t, DC);

    fused_gemm<DU><<<(NU + 63) / 64, 256, 0, stream>>>(xu, Wu_t, bu, Wlo_t, nullptr, pu, NU);
    fused_gemm<DC><<<(NC + 63) / 64, 256, 0, stream>>>(xc, Wc_t, bc, Wro_t, b2, out, NC);

    degree_kernel<<<1024, 256, 0, stream>>>(edst, cnt);
    scan1<<<NBLK, 256, 0, stream>>>(cnt, bsum);
    scan2<<<1, 64, 0, stream>>>(bsum, boff, off);
    scan3<<<NBLK, 256, 0, stream>>>(cnt, boff, off, cursor);
    place_kernel<<<2048, 256, 0, stream>>>(esrc, edst, cursor, ssrc);
    gather_agg<<<(NC + 3) / 4, 256, 0, stream>>>(ssrc, off, pu, out);
}

// Round 4
// 440.695 us; speedup vs baseline: 2.0993x; 1.3833x over previous
//
#include <hip/hip_runtime.h>
#include <hip/hip_bf16.h>

#define NC 100000
#define NU 100000
#define NE 1600000
#define DC 256
#define DU 128
#define HID 128
#define OUTD 64

#define BSHIFT 9
#define BRANGE 512
#define NBUCK ((NC + BRANGE - 1) / BRANGE)   // 196
#define BCAP 10240
#define EPB 8192
#define ABLK ((NE + EPB - 1) / EPB)          // 196

typedef __attribute__((ext_vector_type(8))) short bf16x8;
typedef __attribute__((ext_vector_type(4))) float f32x4;

// RNE float->bf16 (values are finite; no NaN handling needed)
__device__ inline unsigned short f2b(float f) {
    unsigned int u = __float_as_uint(f);
    u += 0x7fffu + ((u >> 16) & 1u);
    return (unsigned short)(u >> 16);
}

// ---------------------------------------------------------------------------
// K0: Wlo_t = (Wl@Wo)^T bf16, Wro_t = (Wr@Wo)^T bf16, b2 = bl@Wo + bo (fp32)
// ---------------------------------------------------------------------------
__global__ void prep_kernel(const float* __restrict__ Wl, const float* __restrict__ bl,
                            const float* __restrict__ Wr, const float* __restrict__ Wo,
                            const float* __restrict__ bo,
                            __hip_bfloat16* __restrict__ Wlo_t,
                            __hip_bfloat16* __restrict__ Wro_t,
                            float* __restrict__ b2) {
    const int k = blockIdx.x;   // 0..127
    const int f = threadIdx.x;  // 0..63
    float a0 = 0.f, a1 = 0.f;
    for (int m = 0; m < HID; ++m) {
        float wo = Wo[m * OUTD + f];
        a0 = fmaf(Wl[k * HID + m], wo, a0);
        a1 = fmaf(Wr[k * HID + m], wo, a1);
    }
    Wlo_t[f * HID + k] = __float2bfloat16(a0);   // [OUTD][HID]
    Wro_t[f * HID + k] = __float2bfloat16(a1);
    if (k == 0) {
        float s = bo[f];
        for (int m = 0; m < HID; ++m) s = fmaf(bl[m], Wo[m * OUTD + f], s);
        b2[f] = s;
    }
}

// ---------------------------------------------------------------------------
// K0b: transpose + bf16-convert input-proj weight: Wt[j][k] = W[k][j]
// ---------------------------------------------------------------------------
__global__ void transpose_w(const float* __restrict__ W, __hip_bfloat16* __restrict__ Wt,
                            int K) {
    int i = blockIdx.x * blockDim.x + threadIdx.x;
    int total = K * HID;
    if (i >= total) return;
    int j = i % HID, k = i / HID;
    Wt[j * K + k] = __float2bfloat16(W[k * HID + j]);
}

// ---------------------------------------------------------------------------
// Fused MFMA pipeline: p = relu(x @ W1 + b1) @ W2 (+bias2)
// 256 thr = 4 waves; 64-row M-tile. BF16OUT: store packed bf16 (no bias2).
// ---------------------------------------------------------------------------
template <int DIN, bool BF16OUT>
__global__ void __launch_bounds__(256) fused_gemm(const float* __restrict__ x,
                                                  const __hip_bfloat16* __restrict__ W1t,
                                                  const float* __restrict__ b1,
                                                  const __hip_bfloat16* __restrict__ W2t,
                                                  const float* __restrict__ bias2,
                                                  void* __restrict__ outp, int nrows) {
    constexpr int PAD = 8;
    constexpr int XS = DIN + PAD;
    constexpr int HS = HID + PAD;
    __shared__ __align__(16) __hip_bfloat16 x_s[64 * XS];
    __shared__ __align__(16) __hip_bfloat16 h_s[64 * HS];
    const int t = threadIdx.x;
    const int wave = t >> 6, lane = t & 63;
    const int quad = lane >> 4, l16 = lane & 15;
    const int base = blockIdx.x * 64;

    // ---- stage 64 x DIN fp32 -> bf16 LDS tile ----
    constexpr int NF4 = 16 * DIN;
    for (int i = t; i < NF4; i += 256) {
        int row = i / (DIN / 4), c4 = i % (DIN / 4);
        float4 v = make_float4(0.f, 0.f, 0.f, 0.f);
        if (base + row < nrows)
            v = ((const float4*)(x + (size_t)(base + row) * DIN))[c4];
        ushort4 w;
        w.x = f2b(v.x); w.y = f2b(v.y); w.z = f2b(v.z); w.w = f2b(v.w);
        *(ushort4*)&x_s[row * XS + c4 * 4] = w;
    }
    __syncthreads();

    // ---- GEMM1: h = relu(x @ W1 + b1) ----
    f32x4 acc1[HID / 16];
#pragma unroll
    for (int nt = 0; nt < HID / 16; ++nt) acc1[nt] = (f32x4){0.f, 0.f, 0.f, 0.f};
#pragma unroll
    for (int ks = 0; ks < DIN / 32; ++ks) {
        bf16x8 a = *(const bf16x8*)&x_s[(wave * 16 + l16) * XS + ks * 32 + quad * 8];
#pragma unroll
        for (int nt = 0; nt < HID / 16; ++nt) {
            bf16x8 b = *(const bf16x8*)&W1t[(size_t)(nt * 16 + l16) * DIN + ks * 32 + quad * 8];
            acc1[nt] = __builtin_amdgcn_mfma_f32_16x16x32_bf16(a, b, acc1[nt], 0, 0, 0);
        }
    }
#pragma unroll
    for (int nt = 0; nt < HID / 16; ++nt) {
        float bb = b1[nt * 16 + l16];
#pragma unroll
        for (int r = 0; r < 4; ++r) {
            float v = fmaxf(acc1[nt][r] + bb, 0.f);
            h_s[(wave * 16 + quad * 4 + r) * HS + nt * 16 + l16] = __float2bfloat16(v);
        }
    }

    // ---- GEMM2: p = h @ W2 (+bias2) ----
    f32x4 acc2[OUTD / 16];
#pragma unroll
    for (int nt = 0; nt < OUTD / 16; ++nt) acc2[nt] = (f32x4){0.f, 0.f, 0.f, 0.f};
#pragma unroll
    for (int ks = 0; ks < HID / 32; ++ks) {
        bf16x8 a = *(const bf16x8*)&h_s[(wave * 16 + l16) * HS + ks * 32 + quad * 8];
#pragma unroll
        for (int nt = 0; nt < OUTD / 16; ++nt) {
            bf16x8 b = *(const bf16x8*)&W2t[(size_t)(nt * 16 + l16) * HID + ks * 32 + quad * 8];
            acc2[nt] = __builtin_amdgcn_mfma_f32_16x16x32_bf16(a, b, acc2[nt], 0, 0, 0);
        }
    }
#pragma unroll
    for (int nt = 0; nt < OUTD / 16; ++nt) {
        float bb = BF16OUT ? 0.f : bias2[nt * 16 + l16];
#pragma unroll
        for (int r = 0; r < 4; ++r) {
            int row = wave * 16 + quad * 4 + r;
            if (base + row < nrows) {
                if (BF16OUT)
                    ((unsigned short*)outp)[(size_t)(base + row) * OUTD + nt * 16 + l16] =
                        f2b(acc2[nt][r]);
                else
                    ((float*)outp)[(size_t)(base + row) * OUTD + nt * 16 + l16] =
                        acc2[nt][r] + bb;
            }
        }
    }
}

// ---------------------------------------------------------------------------
// Phase A: LDS-bucketed scatter of edges into NBUCK coarse buckets.
// Packed edge: (src << 9) | (dst & 511). One global atomic per bucket/block.
// ---------------------------------------------------------------------------
__global__ void __launch_bounds__(256) bucket_a(const int* __restrict__ src,
                                                const int* __restrict__ dst,
                                                int* __restrict__ gcur,
                                                unsigned int* __restrict__ bke) {
    __shared__ unsigned int pk[EPB];      // 32 KB
    __shared__ int hist[NBUCK];
    __shared__ int lbase[NBUCK];
    __shared__ int lcur[NBUCK];
    __shared__ int gb[NBUCK];
    __shared__ int ts[256];
    const int t = threadIdx.x;
    const int base = blockIdx.x * EPB;
    for (int i = t; i < NBUCK; i += 256) hist[i] = 0;
    __syncthreads();
#pragma unroll
    for (int k = 0; k < EPB / 256; ++k) {
        int e = base + k * 256 + t;
        if (e < NE) atomicAdd(&hist[dst[e] >> BSHIFT], 1);
    }
    __syncthreads();
    int h = (t < NBUCK) ? hist[t] : 0;
    ts[t] = h;
    __syncthreads();
    for (int d = 1; d < 256; d <<= 1) {
        int x = (t >= d) ? ts[t - d] : 0;
        __syncthreads();
        ts[t] += x;
        __syncthreads();
    }
    if (t < NBUCK) {
        int ex = ts[t] - h;
        lbase[t] = ex;
        lcur[t] = ex;
        gb[t] = atomicAdd(&gcur[t], h);
    }
    __syncthreads();
#pragma unroll
    for (int k = 0; k < EPB / 256; ++k) {
        int e = base + k * 256 + t;
        if (e < NE) {
            int s = src[e], d = dst[e];
            int b = d >> BSHIFT;
            int p = atomicAdd(&lcur[b], 1);
            pk[p] = ((unsigned int)s << BSHIFT) | (unsigned int)(d & (BRANGE - 1));
        }
    }
    __syncthreads();
    const int wv = t >> 6, ln = t & 63;
    for (int b = wv; b < NBUCK; b += 4) {
        int s0 = lbase[b], c = hist[b], g0 = gb[b];
        for (int j = ln; j < c; j += 64) {
            int pos = g0 + j;
            if (pos < BCAP) bke[(size_t)b * BCAP + pos] = pk[s0 + j];
        }
    }
}

// ---------------------------------------------------------------------------
// Mid: exclusive scan of bucket totals -> gbase; off[NC] = NE
// ---------------------------------------------------------------------------
__global__ void scan_mid(const int* __restrict__ gcur, int* __restrict__ gbase,
                         int* __restrict__ off) {
    __shared__ int ts[256];
    int t = threadIdx.x;
    int h = (t < NBUCK) ? gcur[t] : 0;
    ts[t] = h;
    __syncthreads();
    for (int d = 1; d < 256; d <<= 1) {
        int x = (t >= d) ? ts[t - d] : 0;
        __syncthreads();
        ts[t] += x;
        __syncthreads();
    }
    if (t < NBUCK) gbase[t] = ts[t] - h;
    if (t == 0) { gbase[NBUCK] = NE; off[NC] = NE; }
}

// ---------------------------------------------------------------------------
// Phase B: per-bucket counting sort in LDS -> off[] + ssrc[] (dense writes)
// ---------------------------------------------------------------------------
__global__ void __launch_bounds__(256) bucket_b(const int* __restrict__ gcur,
                                                const int* __restrict__ gbase,
                                                const unsigned int* __restrict__ bke,
                                                int* __restrict__ off,
                                                int* __restrict__ ssrc) {
    __shared__ unsigned int pk[BCAP];     // 40 KB
    __shared__ int hist[BRANGE];
    __shared__ int hb[BRANGE];
    __shared__ int cur[BRANGE];
    __shared__ int ts[256];
    const int t = threadIdx.x;
    const int b = blockIdx.x;
    const int n = min(gcur[b], BCAP);
    const int g0 = gbase[b];
    for (int i = t; i < n; i += 256) pk[i] = bke[(size_t)b * BCAP + i];
    for (int i = t; i < BRANGE; i += 256) hist[i] = 0;
    __syncthreads();
    for (int i = t; i < n; i += 256) atomicAdd(&hist[pk[i] & (BRANGE - 1)], 1);
    __syncthreads();
    int a0 = hist[2 * t], a1 = hist[2 * t + 1];
    int s = a0 + a1;
    ts[t] = s;
    __syncthreads();
    for (int d = 1; d < 256; d <<= 1) {
        int x = (t >= d) ? ts[t - d] : 0;
        __syncthreads();
        ts[t] += x;
        __syncthreads();
    }
    int ex = ts[t] - s;
    hb[2 * t] = ex;
    hb[2 * t + 1] = ex + a0;
    __syncthreads();
    for (int i = t; i < BRANGE; i += 256) {
        int node = b * BRANGE + i;
        cur[i] = g0 + hb[i];
        if (node < NC) off[node] = g0 + hb[i];
    }
    __syncthreads();
    for (int i = t; i < n; i += 256) {
        unsigned int v = pk[i];
        int p = atomicAdd(&cur[v & (BRANGE - 1)], 1);
        ssrc[p] = (int)(v >> BSHIFT);
    }
}

// ---------------------------------------------------------------------------
// Gather-aggregate (bf16 pu) + mean + add into out. One wave per node.
// Lane layout: g = lane>>3 (8 edge slots), f8 = lane&7 (16B chunk of 128B row)
// ---------------------------------------------------------------------------
__global__ void __launch_bounds__(256) gather_agg(const int* __restrict__ ssrc,
                                                  const int* __restrict__ off,
                                                  const unsigned int* __restrict__ pu,
                                                  float* __restrict__ out) {
    int node = blockIdx.x * 4 + (threadIdx.x >> 6);
    if (node >= NC) return;
    int lane = threadIdx.x & 63;
    int g = lane >> 3;
    int f8 = lane & 7;
    int e0 = off[node], e1 = off[node + 1];
    float acc[8] = {0.f, 0.f, 0.f, 0.f, 0.f, 0.f, 0.f, 0.f};
    for (int e = e0 + g; e < e1; e += 8) {
        int s = ssrc[e];
        uint4 v = ((const uint4*)pu)[(size_t)s * 8 + f8];
        acc[0] += __uint_as_float(v.x << 16);
        acc[1] += __uint_as_float(v.x & 0xffff0000u);
        acc[2] += __uint_as_float(v.y << 16);
        acc[3] += __uint_as_float(v.y & 0xffff0000u);
        acc[4] += __uint_as_float(v.z << 16);
        acc[5] += __uint_as_float(v.z & 0xffff0000u);
        acc[6] += __uint_as_float(v.w << 16);
        acc[7] += __uint_as_float(v.w & 0xffff0000u);
    }
#pragma unroll
    for (int m = 8; m <= 32; m <<= 1) {
#pragma unroll
        for (int j = 0; j < 8; ++j) acc[j] += __shfl_xor(acc[j], m, 64);
    }
    if (g == 0) {
        float inv = 1.0f / (float)max(e1 - e0, 1);
        float4* po = (float4*)(out + (size_t)node * OUTD + f8 * 8);
        float4 o0 = po[0], o1 = po[1];
        o0.x += acc[0] * inv; o0.y += acc[1] * inv;
        o0.z += acc[2] * inv; o0.w += acc[3] * inv;
        o1.x += acc[4] * inv; o1.y += acc[5] * inv;
        o1.z += acc[6] * inv; o1.w += acc[7] * inv;
        po[0] = o0; po[1] = o1;
    }
}

extern "C" void kernel_launch(void* const* d_in, const int* in_sizes, int n_in,
                              void* d_out, int out_size, void* d_ws, size_t ws_size,
                              hipStream_t stream) {
    const float* xc = (const float*)d_in[0];
    const float* xu = (const float*)d_in[1];
    const int*   ei = (const int*)d_in[2];
    const float* Wc = (const float*)d_in[3];
    const float* bc = (const float*)d_in[4];
    const float* Wu = (const float*)d_in[5];
    const float* bu = (const float*)d_in[6];
    const float* Wl = (const float*)d_in[7];
    const float* bl = (const float*)d_in[8];
    const float* Wr = (const float*)d_in[9];
    const float* Wo = (const float*)d_in[10];
    const float* bo = (const float*)d_in[11];
    float* out = (float*)d_out;

    const int* esrc = ei;        // edge_index[0] = user ids
    const int* edst = ei + NE;   // edge_index[1] = content ids

    // workspace carve (all chunk sizes multiples of 16 B)
    unsigned short* pu = (unsigned short*)d_ws;             // NU*64 bf16 (12.8 MB)
    int* ssrc  = (int*)(pu + (size_t)NU * OUTD);            // NE (6.4 MB)
    unsigned int* bke = (unsigned int*)(ssrc + NE);         // NBUCK*BCAP (8.03 MB)
    int* gcur  = (int*)(bke + (size_t)NBUCK * BCAP);        // 196
    int* gbase = gcur + NBUCK;                              // 197 (+pad to 400 total)
    int* off   = gcur + 400;                                // NC+1 (+pad to NC+4)
    float* b2  = (float*)(off + NC + 4);                    // 64
    __hip_bfloat16* Wlo_t = (__hip_bfloat16*)(b2 + OUTD);   // 64*128
    __hip_bfloat16* Wro_t = Wlo_t + OUTD * HID;             // 64*128
    __hip_bfloat16* Wu_t  = Wro_t + OUTD * HID;             // 128*128
    __hip_bfloat16* Wc_t  = Wu_t + HID * DU;                // 128*256

    hipMemsetAsync(gcur, 0, NBUCK * sizeof(int), stream);

    prep_kernel<<<HID, OUTD, 0, stream>>>(Wl, bl, Wr, Wo, bo, Wlo_t, Wro_t, b2);
    transpose_w<<<(DU * HID + 255) / 256, 256, 0, stream>>>(Wu, Wu_t, DU);
    transpose_w<<<(DC * HID + 255) / 256, 256, 0, stream>>>(Wc, Wc_t, DC);

    fused_gemm<DU, true><<<(NU + 63) / 64, 256, 0, stream>>>(
        xu, Wu_t, bu, Wlo_t, nullptr, pu, NU);
    fused_gemm<DC, false><<<(NC + 63) / 64, 256, 0, stream>>>(
        xc, Wc_t, bc, Wro_t, b2, out, NC);

    bucket_a<<<ABLK, 256, 0, stream>>>(esrc, edst, gcur, bke);
    scan_mid<<<1, 256, 0, stream>>>(gcur, gbase, off);
    bucket_b<<<NBUCK, 256, 0, stream>>>(gcur, gbase, bke, off, ssrc);
    gather_agg<<<(NC + 3) / 4, 256, 0, stream>>>(ssrc, off, (const unsigned int*)pu, out);
}

// Round 5
// 418.281 us; speedup vs baseline: 2.2118x; 1.0536x over previous
//
#include <hip/hip_runtime.h>
#include <hip/hip_bf16.h>

#define NC 100000
#define NU 100000
#define NE 1600000
#define DC 256
#define DU 128
#define HID 128
#define OUTD 64

#define BSHIFT 9
#define BRANGE 512
#define NBUCK ((NC + BRANGE - 1) / BRANGE)   // 196
#define BCAP 10240
#define EPB 8192
#define ABLK ((NE + EPB - 1) / EPB)          // 196

#define NBT_C ((NC + 63) / 64)               // 1563
#define NBT_U ((NU + 63) / 64)               // 1563

#define HS (HID + 4)   // 132 shorts = 264 B row stride: quad stride 8 banks, <=2-way

typedef __attribute__((ext_vector_type(8))) short bf16x8;
typedef __attribute__((ext_vector_type(4))) float f32x4;

// RNE float->bf16 (finite inputs)
__device__ inline unsigned short f2b(float f) {
    unsigned int u = __float_as_uint(f);
    u += 0x7fffu + ((u >> 16) & 1u);
    return (unsigned short)(u >> 16);
}

// ---------------------------------------------------------------------------
// K0: Wlo_t = (Wl@Wo)^T bf16, Wro_t = (Wr@Wo)^T bf16, b2 = bl@Wo + bo (fp32)
// ---------------------------------------------------------------------------
__global__ void prep_kernel(const float* __restrict__ Wl, const float* __restrict__ bl,
                            const float* __restrict__ Wr, const float* __restrict__ Wo,
                            const float* __restrict__ bo,
                            __hip_bfloat16* __restrict__ Wlo_t,
                            __hip_bfloat16* __restrict__ Wro_t,
                            float* __restrict__ b2) {
    const int k = blockIdx.x;   // 0..127
    const int f = threadIdx.x;  // 0..63
    float a0 = 0.f, a1 = 0.f;
    for (int m = 0; m < HID; ++m) {
        float wo = Wo[m * OUTD + f];
        a0 = fmaf(Wl[k * HID + m], wo, a0);
        a1 = fmaf(Wr[k * HID + m], wo, a1);
    }
    Wlo_t[f * HID + k] = __float2bfloat16(a0);   // [OUTD][HID]
    Wro_t[f * HID + k] = __float2bfloat16(a1);
    if (k == 0) {
        float s = bo[f];
        for (int m = 0; m < HID; ++m) s = fmaf(bl[m], Wo[m * OUTD + f], s);
        b2[f] = s;
    }
}

// ---------------------------------------------------------------------------
// K0b: transpose + bf16-convert input-proj weight: Wt[j][k] = W[k][j]
// ---------------------------------------------------------------------------
__global__ void transpose_w(const float* __restrict__ W, __hip_bfloat16* __restrict__ Wt,
                            int K) {
    int i = blockIdx.x * blockDim.x + threadIdx.x;
    int total = K * HID;
    if (i >= total) return;
    int j = i % HID, k = i / HID;
    Wt[j * K + k] = __float2bfloat16(W[k * HID + j]);
}

// ---------------------------------------------------------------------------
// Device GEMM path: p = relu(x @ W1 + b1) @ W2 (+bias2)
// A-fragments loaded DIRECTLY from global (no x LDS tile: zero reuse there).
// h round-trips through LDS (C-layout -> A-layout transform).
// ---------------------------------------------------------------------------
template <int DIN, bool BF16OUT>
__device__ __forceinline__ void gemm_path(const float* __restrict__ x,
                                          const __hip_bfloat16* __restrict__ W1t,
                                          const float* __restrict__ b1,
                                          const __hip_bfloat16* __restrict__ W2t,
                                          const float* __restrict__ bias2,
                                          void* __restrict__ outp, int nrows, int tile,
                                          __hip_bfloat16* h_s) {
    const int t = threadIdx.x;
    const int wave = t >> 6, lane = t & 63;
    const int quad = lane >> 4, l16 = lane & 15;
    const int base = tile * 64;
    const int row = base + wave * 16 + l16;
    const int rowc = min(row, nrows - 1);   // clamp; garbage stays in this row, masked at store

    // ---- load + convert all A-fragments for this row (16B-aligned, coalesced) ----
    constexpr int NKS = DIN / 32;
    bf16x8 abf[NKS];
#pragma unroll
    for (int ks = 0; ks < NKS; ++ks) {
        const float4* xr = (const float4*)(x + (size_t)rowc * DIN) + ks * 8 + quad * 2;
        float4 v0 = xr[0];
        float4 v1 = xr[1];
        bf16x8 a;
        a[0] = (short)f2b(v0.x); a[1] = (short)f2b(v0.y);
        a[2] = (short)f2b(v0.z); a[3] = (short)f2b(v0.w);
        a[4] = (short)f2b(v1.x); a[5] = (short)f2b(v1.y);
        a[6] = (short)f2b(v1.z); a[7] = (short)f2b(v1.w);
        abf[ks] = a;
    }

    // ---- GEMM1: h = relu(x @ W1 + b1) ----
    f32x4 acc1[HID / 16];
#pragma unroll
    for (int nt = 0; nt < HID / 16; ++nt) acc1[nt] = (f32x4){0.f, 0.f, 0.f, 0.f};
#pragma unroll
    for (int ks = 0; ks < NKS; ++ks) {
#pragma unroll
        for (int nt = 0; nt < HID / 16; ++nt) {
            bf16x8 b = *(const bf16x8*)&W1t[(size_t)(nt * 16 + l16) * DIN + ks * 32 + quad * 8];
            acc1[nt] = __builtin_amdgcn_mfma_f32_16x16x32_bf16(abf[ks], b, acc1[nt], 0, 0, 0);
        }
    }
    // epilogue 1: +bias, relu, bf16 -> h_s (wave-private rows, no barrier needed)
#pragma unroll
    for (int nt = 0; nt < HID / 16; ++nt) {
        float bb = b1[nt * 16 + l16];
#pragma unroll
        for (int r = 0; r < 4; ++r) {
            float v = fmaxf(acc1[nt][r] + bb, 0.f);
            h_s[(wave * 16 + quad * 4 + r) * HS + nt * 16 + l16] = __float2bfloat16(v);
        }
    }

    // ---- GEMM2: p = h @ W2 (+bias2) ----
    f32x4 acc2[OUTD / 16];
#pragma unroll
    for (int nt = 0; nt < OUTD / 16; ++nt) acc2[nt] = (f32x4){0.f, 0.f, 0.f, 0.f};
#pragma unroll
    for (int ks = 0; ks < HID / 32; ++ks) {
        bf16x8 a = *(const bf16x8*)&h_s[(wave * 16 + l16) * HS + ks * 32 + quad * 8];
#pragma unroll
        for (int nt = 0; nt < OUTD / 16; ++nt) {
            bf16x8 b = *(const bf16x8*)&W2t[(size_t)(nt * 16 + l16) * HID + ks * 32 + quad * 8];
            acc2[nt] = __builtin_amdgcn_mfma_f32_16x16x32_bf16(a, b, acc2[nt], 0, 0, 0);
        }
    }
#pragma unroll
    for (int nt = 0; nt < OUTD / 16; ++nt) {
        float bb = BF16OUT ? 0.f : bias2[nt * 16 + l16];
#pragma unroll
        for (int r = 0; r < 4; ++r) {
            int rr = base + wave * 16 + quad * 4 + r;
            if (rr < nrows) {
                if (BF16OUT)
                    ((unsigned short*)outp)[(size_t)rr * OUTD + nt * 16 + l16] =
                        f2b(acc2[nt][r]);
                else
                    ((float*)outp)[(size_t)rr * OUTD + nt * 16 + l16] = acc2[nt][r] + bb;
            }
        }
    }
}

// ---------------------------------------------------------------------------
// Dual GEMM: content blocks [0, NBT_C), user blocks [NBT_C, NBT_C+NBT_U)
// ---------------------------------------------------------------------------
__global__ void __launch_bounds__(256) dual_gemm(
    const float* __restrict__ xc, const __hip_bfloat16* __restrict__ Wc_t,
    const float* __restrict__ bc, const __hip_bfloat16* __restrict__ Wro_t,
    const float* __restrict__ b2, float* __restrict__ out,
    const float* __restrict__ xu, const __hip_bfloat16* __restrict__ Wu_t,
    const float* __restrict__ bu, const __hip_bfloat16* __restrict__ Wlo_t,
    unsigned short* __restrict__ pu) {
    __shared__ __align__(16) __hip_bfloat16 h_s[64 * HS];
    int b = blockIdx.x;
    if (b < NBT_C)
        gemm_path<DC, false>(xc, Wc_t, bc, Wro_t, b2, out, NC, b, h_s);
    else
        gemm_path<DU, true>(xu, Wu_t, bu, Wlo_t, nullptr, pu, NU, b - NBT_C, h_s);
}

// ---------------------------------------------------------------------------
// Phase A: LDS-bucketed scatter of edges into NBUCK coarse buckets.
// ---------------------------------------------------------------------------
__global__ void __launch_bounds__(256) bucket_a(const int* __restrict__ src,
                                                const int* __restrict__ dst,
                                                int* __restrict__ gcur,
                                                unsigned int* __restrict__ bke) {
    __shared__ unsigned int pk[EPB];      // 32 KB
    __shared__ int hist[NBUCK];
    __shared__ int lbase[NBUCK];
    __shared__ int lcur[NBUCK];
    __shared__ int gb[NBUCK];
    __shared__ int ts[256];
    const int t = threadIdx.x;
    const int base = blockIdx.x * EPB;
    for (int i = t; i < NBUCK; i += 256) hist[i] = 0;
    __syncthreads();
#pragma unroll
    for (int k = 0; k < EPB / 256; ++k) {
        int e = base + k * 256 + t;
        if (e < NE) atomicAdd(&hist[dst[e] >> BSHIFT], 1);
    }
    __syncthreads();
    int h = (t < NBUCK) ? hist[t] : 0;
    ts[t] = h;
    __syncthreads();
    for (int d = 1; d < 256; d <<= 1) {
        int x = (t >= d) ? ts[t - d] : 0;
        __syncthreads();
        ts[t] += x;
        __syncthreads();
    }
    if (t < NBUCK) {
        int ex = ts[t] - h;
        lbase[t] = ex;
        lcur[t] = ex;
        gb[t] = atomicAdd(&gcur[t], h);
    }
    __syncthreads();
#pragma unroll
    for (int k = 0; k < EPB / 256; ++k) {
        int e = base + k * 256 + t;
        if (e < NE) {
            int s = src[e], d = dst[e];
            int b = d >> BSHIFT;
            int p = atomicAdd(&lcur[b], 1);
            pk[p] = ((unsigned int)s << BSHIFT) | (unsigned int)(d & (BRANGE - 1));
        }
    }
    __syncthreads();
    const int wv = t >> 6, ln = t & 63;
    for (int b = wv; b < NBUCK; b += 4) {
        int s0 = lbase[b], c = hist[b], g0 = gb[b];
        for (int j = ln; j < c; j += 64) {
            int pos = g0 + j;
            if (pos < BCAP) bke[(size_t)b * BCAP + pos] = pk[s0 + j];
        }
    }
}

// ---------------------------------------------------------------------------
// Mid: exclusive scan of bucket totals -> gbase; off[NC] = NE
// ---------------------------------------------------------------------------
__global__ void scan_mid(const int* __restrict__ gcur, int* __restrict__ gbase,
                         int* __restrict__ off) {
    __shared__ int ts[256];
    int t = threadIdx.x;
    int h = (t < NBUCK) ? gcur[t] : 0;
    ts[t] = h;
    __syncthreads();
    for (int d = 1; d < 256; d <<= 1) {
        int x = (t >= d) ? ts[t - d] : 0;
        __syncthreads();
        ts[t] += x;
        __syncthreads();
    }
    if (t < NBUCK) gbase[t] = ts[t] - h;
    if (t == 0) { gbase[NBUCK] = NE; off[NC] = NE; }
}

// ---------------------------------------------------------------------------
// Phase B: per-bucket counting sort in LDS -> off[] + ssrc[] (dense writes)
// ---------------------------------------------------------------------------
__global__ void __launch_bounds__(256) bucket_b(const int* __restrict__ gcur,
                                                const int* __restrict__ gbase,
                                                const unsigned int* __restrict__ bke,
                                                int* __restrict__ off,
                                                int* __restrict__ ssrc) {
    __shared__ unsigned int pk[BCAP];     // 40 KB
    __shared__ int hist[BRANGE];
    __shared__ int hb[BRANGE];
    __shared__ int cur[BRANGE];
    __shared__ int ts[256];
    const int t = threadIdx.x;
    const int b = blockIdx.x;
    const int n = min(gcur[b], BCAP);
    const int g0 = gbase[b];
    for (int i = t; i < n; i += 256) pk[i] = bke[(size_t)b * BCAP + i];
    for (int i = t; i < BRANGE; i += 256) hist[i] = 0;
    __syncthreads();
    for (int i = t; i < n; i += 256) atomicAdd(&hist[pk[i] & (BRANGE - 1)], 1);
    __syncthreads();
    int a0 = hist[2 * t], a1 = hist[2 * t + 1];
    int s = a0 + a1;
    ts[t] = s;
    __syncthreads();
    for (int d = 1; d < 256; d <<= 1) {
        int x = (t >= d) ? ts[t - d] : 0;
        __syncthreads();
        ts[t] += x;
        __syncthreads();
    }
    int ex = ts[t] - s;
    hb[2 * t] = ex;
    hb[2 * t + 1] = ex + a0;
    __syncthreads();
    for (int i = t; i < BRANGE; i += 256) {
        int node = b * BRANGE + i;
        cur[i] = g0 + hb[i];
        if (node < NC) off[node] = g0 + hb[i];
    }
    __syncthreads();
    for (int i = t; i < n; i += 256) {
        unsigned int v = pk[i];
        int p = atomicAdd(&cur[v & (BRANGE - 1)], 1);
        ssrc[p] = (int)(v >> BSHIFT);
    }
}

// ---------------------------------------------------------------------------
// Gather-aggregate (bf16 pu) + mean + add into out. One wave per node.
// ---------------------------------------------------------------------------
__global__ void __launch_bounds__(256) gather_agg(const int* __restrict__ ssrc,
                                                  const int* __restrict__ off,
                                                  const unsigned int* __restrict__ pu,
                                                  float* __restrict__ out) {
    int node = blockIdx.x * 4 + (threadIdx.x >> 6);
    if (node >= NC) return;
    int lane = threadIdx.x & 63;
    int g = lane >> 3;
    int f8 = lane & 7;
    int e0 = off[node], e1 = off[node + 1];
    float acc[8] = {0.f, 0.f, 0.f, 0.f, 0.f, 0.f, 0.f, 0.f};
    for (int e = e0 + g; e < e1; e += 8) {
        int s = ssrc[e];
        uint4 v = ((const uint4*)pu)[(size_t)s * 8 + f8];
        acc[0] += __uint_as_float(v.x << 16);
        acc[1] += __uint_as_float(v.x & 0xffff0000u);
        acc[2] += __uint_as_float(v.y << 16);
        acc[3] += __uint_as_float(v.y & 0xffff0000u);
        acc[4] += __uint_as_float(v.z << 16);
        acc[5] += __uint_as_float(v.z & 0xffff0000u);
        acc[6] += __uint_as_float(v.w << 16);
        acc[7] += __uint_as_float(v.w & 0xffff0000u);
    }
#pragma unroll
    for (int m = 8; m <= 32; m <<= 1) {
#pragma unroll
        for (int j = 0; j < 8; ++j) acc[j] += __shfl_xor(acc[j], m, 64);
    }
    if (g == 0) {
        float inv = 1.0f / (float)max(e1 - e0, 1);
        float4* po = (float4*)(out + (size_t)node * OUTD + f8 * 8);
        float4 o0 = po[0], o1 = po[1];
        o0.x += acc[0] * inv; o0.y += acc[1] * inv;
        o0.z += acc[2] * inv; o0.w += acc[3] * inv;
        o1.x += acc[4] * inv; o1.y += acc[5] * inv;
        o1.z += acc[6] * inv; o1.w += acc[7] * inv;
        po[0] = o0; po[1] = o1;
    }
}

extern "C" void kernel_launch(void* const* d_in, const int* in_sizes, int n_in,
                              void* d_out, int out_size, void* d_ws, size_t ws_size,
                              hipStream_t stream) {
    const float* xc = (const float*)d_in[0];
    const float* xu = (const float*)d_in[1];
    const int*   ei = (const int*)d_in[2];
    const float* Wc = (const float*)d_in[3];
    const float* bc = (const float*)d_in[4];
    const float* Wu = (const float*)d_in[5];
    const float* bu = (const float*)d_in[6];
    const float* Wl = (const float*)d_in[7];
    const float* bl = (const float*)d_in[8];
    const float* Wr = (const float*)d_in[9];
    const float* Wo = (const float*)d_in[10];
    const float* bo = (const float*)d_in[11];
    float* out = (float*)d_out;

    const int* esrc = ei;        // edge_index[0] = user ids
    const int* edst = ei + NE;   // edge_index[1] = content ids

    // workspace carve (all chunk sizes multiples of 16 B)
    unsigned short* pu = (unsigned short*)d_ws;             // NU*64 bf16 (12.8 MB)
    int* ssrc  = (int*)(pu + (size_t)NU * OUTD);            // NE (6.4 MB)
    unsigned int* bke = (unsigned int*)(ssrc + NE);         // NBUCK*BCAP (8.03 MB)
    int* gcur  = (int*)(bke + (size_t)NBUCK * BCAP);        // 196
    int* gbase = gcur + NBUCK;                              // 197 (pad to 400 total)
    int* off   = gcur + 400;                                // NC+1 (pad to NC+4)
    float* b2  = (float*)(off + NC + 4);                    // 64
    __hip_bfloat16* Wlo_t = (__hip_bfloat16*)(b2 + OUTD);   // 64*128
    __hip_bfloat16* Wro_t = Wlo_t + OUTD * HID;             // 64*128
    __hip_bfloat16* Wu_t  = Wro_t + OUTD * HID;             // 128*128
    __hip_bfloat16* Wc_t  = Wu_t + HID * DU;                // 128*256

    hipMemsetAsync(gcur, 0, NBUCK * sizeof(int), stream);

    prep_kernel<<<HID, OUTD, 0, stream>>>(Wl, bl, Wr, Wo, bo, Wlo_t, Wro_t, b2);
    transpose_w<<<(DU * HID + 255) / 256, 256, 0, stream>>>(Wu, Wu_t, DU);
    transpose_w<<<(DC * HID + 255) / 256, 256, 0, stream>>>(Wc, Wc_t, DC);

    dual_gemm<<<NBT_C + NBT_U, 256, 0, stream>>>(xc, Wc_t, bc, Wro_t, b2, out,
                                                 xu, Wu_t, bu, Wlo_t, pu);

    bucket_a<<<ABLK, 256, 0, stream>>>(esrc, edst, gcur, bke);
    scan_mid<<<1, 256, 0, stream>>>(gcur, gbase, off);
    bucket_b<<<NBUCK, 256, 0, stream>>>(gcur, gbase, bke, off, ssrc);
    gather_agg<<<(NC + 3) / 4, 256, 0, stream>>>(ssrc, off, (const unsigned int*)pu, out);
}